// Round 8
// baseline (783.923 us; speedup 1.0000x reference)
//
#include <hip/hip_runtime.h>
#include <stdint.h>

#define B_   16
#define C_   192
#define TX_  512
#define TY_  2048
#define K_   384       // 2*C
#define SEG_ 32
#define NEG_INF_ (-1e9f)

// Output layout (floats) in d_out:
//   z_slice : [16,192,32]    @ 0         (98304)
//   ids     : [16] (as f32)  @ 98304     (16)
//   attn    : [16,2048,512]  @ 98320     (16777216)
//   m_p_a   : [16,192,2048]  @ 16875536  (6291456)
//   logs_p_a: [16,192,2048]  @ 23166992  (6291456)

// ---------------------------------------------------------------------------
// K0: build B-matrix [b, k, tx] (k<192: s = exp(-2 logs); k>=192: s*m_p) and
//     c_term[b,tx] = sum_c (-0.5 s m^2 - logs)
// ---------------------------------------------------------------------------
__global__ __launch_bounds__(128) void k_prep(const float* __restrict__ mp,
                                              const float* __restrict__ logsp,
                                              float* __restrict__ Bmat,
                                              float* __restrict__ cterm) {
    int b  = blockIdx.y;
    int tx = blockIdx.x * 128 + threadIdx.x;
    const float* mb = mp    + (size_t)b * C_ * TX_ + tx;
    const float* lb = logsp + (size_t)b * C_ * TX_ + tx;
    float* B0 = Bmat + (size_t)b * K_ * TX_ + tx;
    float acc = 0.f;
    for (int c = 0; c < C_; ++c) {
        float lg = lb[(size_t)c * TX_];
        float m  = mb[(size_t)c * TX_];
        float s  = expf(-2.f * lg);
        B0[(size_t)c * TX_]        = s;
        B0[(size_t)(C_ + c) * TX_] = s * m;
        acc += -0.5f * s * m * m - lg;
    }
    cterm[b * TX_ + tx] = acc;
}

// ---------------------------------------------------------------------------
// K1: neg_cent GEMM.  C[b, ty, tx] = sum_k A[b,k,ty]*B[b,k,tx] + cterm[b,tx]
//     A is derived on the fly from z_p: k<192 -> -0.5*z^2 ; k>=192 -> z.
//     128x128 tile, 256 threads, 8x8 accumulators/thread, K-block 16.
// ---------------------------------------------------------------------------
__global__ __launch_bounds__(256) void k_gemm(const float* __restrict__ zp,
                                              const float* __restrict__ Bmat,
                                              const float* __restrict__ cterm,
                                              float* __restrict__ ncout) {
    __shared__ float As[16][128];
    __shared__ float Bs[16][128];
    int b  = blockIdx.z;
    int m0 = blockIdx.y * 128;   // ty
    int n0 = blockIdx.x * 128;   // tx
    int tid = threadIdx.x;
    int tm = tid >> 4;           // 0..15
    int tn = tid & 15;           // 0..15
    const float* zpb = zp   + (size_t)b * C_ * TY_;
    const float* Bb  = Bmat + (size_t)b * K_ * TX_;

    float acc[8][8];
#pragma unroll
    for (int i = 0; i < 8; ++i)
#pragma unroll
        for (int j = 0; j < 8; ++j) acc[i][j] = 0.f;

    int lrow = tid >> 5;           // 0..7
    int lcol = (tid & 31) << 2;    // 0..124

    for (int k0 = 0; k0 < K_; k0 += 16) {
        int ksrc = (k0 < C_) ? k0 : (k0 - C_);
        const float* Ab = zpb + (size_t)(ksrc + lrow) * TY_ + m0 + lcol;
        float4 z0 = *(const float4*)Ab;
        float4 z1 = *(const float4*)(Ab + (size_t)8 * TY_);
        if (k0 < C_) {
            z0.x = -0.5f * z0.x * z0.x; z0.y = -0.5f * z0.y * z0.y;
            z0.z = -0.5f * z0.z * z0.z; z0.w = -0.5f * z0.w * z0.w;
            z1.x = -0.5f * z1.x * z1.x; z1.y = -0.5f * z1.y * z1.y;
            z1.z = -0.5f * z1.z * z1.z; z1.w = -0.5f * z1.w * z1.w;
        }
        const float* Bp = Bb + (size_t)(k0 + lrow) * TX_ + n0 + lcol;
        float4 w0 = *(const float4*)Bp;
        float4 w1 = *(const float4*)(Bp + (size_t)8 * TX_);

        __syncthreads();   // prior iteration's reads done before overwrite
        *(float4*)&As[lrow][lcol]     = z0;
        *(float4*)&As[lrow + 8][lcol] = z1;
        *(float4*)&Bs[lrow][lcol]     = w0;
        *(float4*)&Bs[lrow + 8][lcol] = w1;
        __syncthreads();

#pragma unroll
        for (int kk = 0; kk < 16; ++kk) {
            float4 a0 = *(const float4*)&As[kk][tm * 8];
            float4 a1 = *(const float4*)&As[kk][tm * 8 + 4];
            float4 b0 = *(const float4*)&Bs[kk][tn * 8];
            float4 b1 = *(const float4*)&Bs[kk][tn * 8 + 4];
            float a[8]  = {a0.x, a0.y, a0.z, a0.w, a1.x, a1.y, a1.z, a1.w};
            float bb[8] = {b0.x, b0.y, b0.z, b0.w, b1.x, b1.y, b1.z, b1.w};
#pragma unroll
            for (int i = 0; i < 8; ++i)
#pragma unroll
                for (int j = 0; j < 8; ++j)
                    acc[i][j] = fmaf(a[i], bb[j], acc[i][j]);
        }
    }

    float cadd[8];
#pragma unroll
    for (int j = 0; j < 8; ++j) cadd[j] = cterm[b * TX_ + n0 + tn * 8 + j];

#pragma unroll
    for (int i = 0; i < 8; ++i) {
        int row = m0 + tm * 8 + i;
        float* orow = ncout + ((size_t)b * TY_ + row) * TX_ + n0 + tn * 8;
        float4 o0, o1;
        o0.x = acc[i][0] + cadd[0]; o0.y = acc[i][1] + cadd[1];
        o0.z = acc[i][2] + cadd[2]; o0.w = acc[i][3] + cadd[3];
        o1.x = acc[i][4] + cadd[4]; o1.y = acc[i][5] + cadd[5];
        o1.z = acc[i][6] + cadd[6]; o1.w = acc[i][7] + cadd[7];
        *(float4*)orow       = o0;
        *(float4*)(orow + 4) = o1;
    }
}

// ---------------------------------------------------------------------------
// K2: fused DP forward + backward — barrier-phased double buffer.
//
// r7 lesson: per-group handshakes (flag poll ~120cyc ds_read + RELEASE
// cons_ctr store -> compiler emits s_waitcnt vmcnt(0) draining the dirn
// stores EVERY 4 rows) kept per-group time ~2000cyc vs ~450cyc compute.
// Fix: amortize ALL sync to once per 32 rows via __syncthreads-phased
// double buffer. No flags, no atomics.
//
// Block = 512 thr (8 waves): waves 1..7 fill buffer (p+1)%2 with the next
// 32 rows (each wave ~5 rows; float4 loads; granule-swizzled conflict-free
// ds_writes), wave 0 consumes buffer p%2 (8x 4-row groups, straight-line
// so the compiler pipelines ds_reads across groups), then one barrier.
// LDS = 2 x 64 KiB.
//
// DP math: 8 cols/lane, DPP wave_shr:1 for the cross-lane term (r6), no
// masking/clamping (validated r3). dirn bits: dword per (4-row group,
// lane) stored to global gdirs: byte addr ((row>>2)*64+lane)*4+(row&3).
// Rows >= t_y in the last phase are computed on garbage and stored, but
// never consulted by backward (rows < t_y only) — harmless.
//
// Backward: wave 0 walks 64-row windows; all 64 lanes fetch one 4 KB
// contiguous strip (lane L: uint4 x4 at +L*64) into LDS, lane 0 then
// consumes it with the 8-row lo/hi speculative scheme (idx dec <=1/row).
// ---------------------------------------------------------------------------
#define NPROD_ 7

__global__ __launch_bounds__(512, 1) void k_dp(const float* __restrict__ nc,
                                               const int* __restrict__ xl,
                                               const int* __restrict__ yl,
                                               int* __restrict__ path,
                                               unsigned* __restrict__ gdirs32) {
    extern __shared__ unsigned char slds[];   // 2 x 64 KiB row buffers
    float* buf0 = (float*)slds;
    float* buf1 = (float*)(slds + 65536);

    int b    = blockIdx.x;
    int tid  = threadIdx.x;
    int w    = tid >> 6;          // wave id 0..7
    int lane = tid & 63;
    int t_x  = xl[b];
    int t_y  = yl[b]; if (t_y > TY_) t_y = TY_;
    const float* ncb = nc + (size_t)b * TY_ * TX_;
    unsigned* gb32 = gdirs32 + (size_t)b * (TY_ / 4) * 64;
    int nph = (t_y + 31) >> 5;    // 32-row phases (32..64)

    if (w != 0) {
        // ---------------- producers (waves 1..7) ----------------
        {   // prologue: fill phase 0 into buf0
            for (int rr = w - 1; rr < 32; rr += NPROD_) {
                const float4* row = (const float4*)(ncb + (size_t)rr * TX_);
                float4 q0 = row[2 * lane];
                float4 q1 = row[2 * lane + 1];
                *(float4*)(buf0 + rr * 512 + lane * 4)       = q0;
                *(float4*)(buf0 + rr * 512 + 256 + lane * 4) = q1;
            }
        }
        __syncthreads();
        for (int p = 0; p < nph; ++p) {
            if (p + 1 < nph) {
                float* sb = ((p + 1) & 1) ? buf1 : buf0;
                int jbase = (p + 1) * 32;
                for (int rr = w - 1; rr < 32; rr += NPROD_) {
                    const float4* row =
                        (const float4*)(ncb + (size_t)(jbase + rr) * TX_);
                    float4 q0 = row[2 * lane];
                    float4 q1 = row[2 * lane + 1];
                    *(float4*)(sb + rr * 512 + lane * 4)       = q0;
                    *(float4*)(sb + rr * 512 + 256 + lane * 4) = q1;
                }
            }
            __syncthreads();
        }
        return;
    }

    // ---------------- consumer (wave 0) ----------------
    int col0 = lane * 8;
    float v[8];
#pragma unroll
    for (int k = 0; k < 8; ++k) v[k] = (col0 + k == 0) ? 0.f : NEG_INF_;
    const unsigned neg_bits = __float_as_uint(NEG_INF_);

    __syncthreads();   // matches producers' prologue barrier
    for (int p = 0; p < nph; ++p) {
        const float* sb = (p & 1) ? buf1 : buf0;
#pragma unroll
        for (int g = 0; g < 8; ++g) {
            unsigned dw = 0u;
#pragma unroll
            for (int r = 0; r < 4; ++r) {
                const float* rowp = sb + (g * 4 + r) * 512;
                float4 p0 = *(const float4*)(rowp + lane * 4);
                float4 p1 = *(const float4*)(rowp + 256 + lane * 4);
                float rc[8] = {p0.x, p0.y, p0.z, p0.w, p1.x, p1.y, p1.z, p1.w};
                float left = __uint_as_float(__builtin_amdgcn_update_dpp(
                    (int)neg_bits, (int)__float_as_uint(v[7]),
                    0x138 /*wave_shr:1*/, 0xF, 0xF, false));
                unsigned by = 0u;
#pragma unroll
                for (int k = 7; k >= 0; --k) {
                    float vs = (k == 0) ? left : v[k - 1];
                    if (vs > v[k]) by |= (1u << k);
                    v[k] = fmaxf(v[k], vs) + rc[k];
                }
                dw |= by << (8 * r);
            }
            gb32[(p * 8 + g) * 64 + lane] = dw;   // grp <= 511, in-bounds
        }
        __syncthreads();
    }

    // drain dirn stores so our own backward loads see them
    __builtin_amdgcn_s_waitcnt(3952);   // vmcnt(0), lgkm=15, exp=7

    int* pb = path + b * TY_;
    for (int j2 = t_y + lane; j2 < TY_; j2 += 64) pb[j2] = -1;

    // ---------------- backward walk (wave 0 only) ----------------
    const unsigned char* gb = (const unsigned char*)gb32;
    unsigned char* swin = (unsigned char*)buf0;   // 4 KiB window
    int j   = t_y - 1;
    int idx = t_x - 1;
    while (j >= 0) {
        int wbase = (j & ~3) - 60; if (wbase < 0) wbase = 0;  // 4-aligned
        {   // fetch rows wbase..wbase+63 strips: 4 KB contiguous
            const uint4* rp = (const uint4*)(gb + (size_t)(wbase >> 2) * 256);
            uint4 a0 = rp[lane * 4 + 0];
            uint4 a1 = rp[lane * 4 + 1];
            uint4 a2 = rp[lane * 4 + 2];
            uint4 a3 = rp[lane * 4 + 3];
            uint4* wp = (uint4*)(swin + lane * 64);
            wp[0] = a0; wp[1] = a1; wp[2] = a2; wp[3] = a3;
        }
        if (lane == 0) {
            while (j >= wbase) {
                int n = j - wbase + 1; if (n > 8) n = 8;
                int Bhi = idx >> 3;
                int Blo = Bhi - 1; if (Blo < 0) Blo = 0;
                unsigned lo8[8], hi8[8];
#pragma unroll
                for (int r = 0; r < 8; ++r) {
                    if (r < n) {
                        int jr  = j - r;
                        int off = ((jr - wbase) >> 2) * 256 + (jr & 3);
                        lo8[r] = swin[off + Blo * 4];
                        hi8[r] = swin[off + Bhi * 4];
                    }
                }
#pragma unroll
                for (int r = 0; r < 8; ++r) {
                    if (r < n) {
                        pb[j - r] = idx;
                        unsigned byte = ((idx >> 3) == Bhi) ? hi8[r] : lo8[r];
                        idx -= (int)((byte >> (idx & 7)) & 1u);
                    }
                }
                j -= n;
            }
        }
        j = wbase - 1;
        // broadcast not needed: only lane 0's j/idx matter next iter for
        // the fetch base; recompute wbase from lane-0's j via readfirstlane
        j = __shfl(j, 0);
    }
}

// ---------------------------------------------------------------------------
// K4a: attn one-hot write (overwrites the neg_cent scratch region).
// ---------------------------------------------------------------------------
__global__ __launch_bounds__(256) void k_attn(const int* __restrict__ path,
                                              float* __restrict__ attn) {
    int i   = blockIdx.x * 256 + threadIdx.x;   // over B*TY*TX/4
    int tx0 = (i & 127) << 2;                   // TX/4 = 128
    int bty = i >> 7;                           // b*TY + ty
    int p   = path[bty];
    float4 o;
    o.x = (p == tx0)     ? 1.f : 0.f;
    o.y = (p == tx0 + 1) ? 1.f : 0.f;
    o.z = (p == tx0 + 2) ? 1.f : 0.f;
    o.w = (p == tx0 + 3) ? 1.f : 0.f;
    ((float4*)attn)[i] = o;
}

// ---------------------------------------------------------------------------
// K4b: m_p_a / logs_p_a gather: out[b,c,ty] = (path[ty]>=0) ? in[b,c,path] : 0
// ---------------------------------------------------------------------------
__global__ __launch_bounds__(256) void k_proj(const int* __restrict__ path,
                                              const float* __restrict__ mp,
                                              const float* __restrict__ logsp,
                                              float* __restrict__ mpa,
                                              float* __restrict__ logsa) {
    int i   = blockIdx.x * 256 + threadIdx.x;   // over B*C*TY/4
    int ty0 = (i & 511) << 2;                   // TY/4 = 512
    int bc  = i >> 9;                           // b*C + c
    int b   = bc / C_;
    const int4 p4 = *(const int4*)(path + b * TY_ + ty0);
    const float* mrow = mp    + (size_t)bc * TX_;
    const float* lrow = logsp + (size_t)bc * TX_;
    float4 mo, lo;
    mo.x = (p4.x >= 0) ? mrow[p4.x] : 0.f;  lo.x = (p4.x >= 0) ? lrow[p4.x] : 0.f;
    mo.y = (p4.y >= 0) ? mrow[p4.y] : 0.f;  lo.y = (p4.y >= 0) ? lrow[p4.y] : 0.f;
    mo.z = (p4.z >= 0) ? mrow[p4.z] : 0.f;  lo.z = (p4.z >= 0) ? lrow[p4.z] : 0.f;
    mo.w = (p4.w >= 0) ? mrow[p4.w] : 0.f;  lo.w = (p4.w >= 0) ? lrow[p4.w] : 0.f;
    ((float4*)mpa)[i]   = mo;
    ((float4*)logsa)[i] = lo;
}

// ---------------------------------------------------------------------------
// K4c: random segment slice of z + ids output (replicates ref f32 math).
// ---------------------------------------------------------------------------
__global__ __launch_bounds__(256) void k_slice(const float* __restrict__ z,
                                               const int* __restrict__ yl,
                                               const float* __restrict__ ru,
                                               float* __restrict__ zs,
                                               float* __restrict__ oid) {
    int b = blockIdx.x;
    int safe = yl[b]; if (safe > TY_) safe = TY_;
    int idsmax = safe - SEG_; if (idsmax < 0) idsmax = 0;
    int ids = (int)(ru[b] * ((float)idsmax + 1e-8f));
    int lim = safe - ids;
    for (int t = threadIdx.x; t < C_ * SEG_; t += 256) {
        int c = t >> 5, k = t & 31;
        zs[b * C_ * SEG_ + t] =
            (k < lim) ? z[((size_t)b * C_ + c) * TY_ + ids + k] : 0.f;
    }
    if (threadIdx.x == 0) oid[b] = (float)ids;
}

// ---------------------------------------------------------------------------
extern "C" void kernel_launch(void* const* d_in, const int* in_sizes, int n_in,
                              void* d_out, int out_size, void* d_ws, size_t ws_size,
                              hipStream_t stream) {
    const float* z     = (const float*)d_in[0];
    const float* zp    = (const float*)d_in[1];
    const float* mp    = (const float*)d_in[2];
    const float* logsp = (const float*)d_in[3];
    const int*   xl    = (const int*)d_in[4];
    const int*   yl    = (const int*)d_in[5];
    const float* ru    = (const float*)d_in[6];

    float* out     = (float*)d_out;
    float* o_zs    = out;                  // 98304
    float* o_ids   = out + 98304;          // 16
    float* o_attn  = out + 98320;          // 16777216 (also neg_cent scratch)
    float* o_mpa   = out + 16875536;       // 6291456
    float* o_logsa = out + 23166992;       // 6291456

    float*    Bmat  = (float*)d_ws;                      // 3,145,728 f
    float*    cterm = Bmat + (size_t)B_ * K_ * TX_;      // 8192 f
    int*      path  = (int*)(cterm + B_ * TX_);          // 32768 i32
    unsigned* gdirs = (unsigned*)(path + B_ * TY_);      // 2 MB dirn bits

    const int dp_lds = 2 * 65536;

    // allow >64 KiB dynamic LDS for the fused DP kernel (host-side, not a
    // stream op — safe under graph capture; idempotent, called every launch)
    hipFuncSetAttribute((const void*)k_dp,
                        hipFuncAttributeMaxDynamicSharedMemorySize, dp_lds);

    hipLaunchKernelGGL(k_prep, dim3(TX_ / 128, B_), dim3(128), 0, stream,
                       mp, logsp, Bmat, cterm);
    hipLaunchKernelGGL(k_gemm, dim3(TX_ / 128, TY_ / 128, B_), dim3(256), 0, stream,
                       zp, Bmat, cterm, o_attn);
    hipLaunchKernelGGL(k_dp, dim3(B_), dim3(512), dp_lds, stream,
                       o_attn, xl, yl, path, gdirs);
    hipLaunchKernelGGL(k_attn, dim3(B_ * TY_ * TX_ / 4 / 256), dim3(256), 0, stream,
                       path, o_attn);
    hipLaunchKernelGGL(k_proj, dim3(B_ * C_ * TY_ / 4 / 256), dim3(256), 0, stream,
                       path, mp, logsp, o_mpa, o_logsa);
    hipLaunchKernelGGL(k_slice, dim3(B_), dim3(256), 0, stream,
                       z, yl, ru, o_zs, o_ids);
}